// Round 13
// baseline (258.479 us; speedup 1.0000x reference)
//
#include <hip/hip_runtime.h>
#include <math.h>

typedef unsigned short u16;
typedef unsigned int   u32;
typedef __bf16 bf16x8 __attribute__((ext_vector_type(8)));
typedef float  f32x4  __attribute__((ext_vector_type(4)));

// B=4 S=2048 D=1024 H=16 Dh=64 -> BH=64 chains, 32 chunks of 64
#define NBATCH 4
#define SEQ    2048
#define DIM    1024
#define NH     16
#define BH     64
#define NC     32
#define ROWS   8192
#define N1     3328   /* 3072 qkv cols + 48 gate cols padded to 256 for 256-wide tiles */

__device__ __forceinline__ u16 f2bf(float f) {
  u32 u = __builtin_bit_cast(u32, f);
  u32 r = u + 0x7fffu + ((u >> 16) & 1u);
  return (u16)(r >> 16);
}
__device__ __forceinline__ float bf2f(u16 h) {
  return __builtin_bit_cast(float, (u32)h << 16);
}

// async global->LDS, 16B per lane; LDS dest = wave-uniform base + lane*16
__device__ __forceinline__ void gl2lds16(const u16* g, u16* l) {
  __builtin_amdgcn_global_load_lds(
      (const __attribute__((address_space(1))) u32*)g,
      (__attribute__((address_space(3))) u32*)l, 16, 0, 0);
}

// ---------------- fused prep: rmsnorm (blocks 0..8191) + weight transposes/gate fill ----
// grid 8192 + 129*32 = 12320 blocks, 256 threads.
__global__ __launch_bounds__(256) void prep_all(const float* __restrict__ x,
                                                const float* __restrict__ w_rms,
                                                u16* __restrict__ xn,
                                                const float* __restrict__ Wqkv,
                                                const float* __restrict__ Wout,
                                                const float* __restrict__ wg,
                                                u16* __restrict__ BtQkv, u16* __restrict__ BtOut) {
  __shared__ float tile[32][33];
  __shared__ float red[4];
  const int bid = blockIdx.x;
  if (bid < 8192) {
    // ---- RMSNorm row ----
    const int row = bid, tid = threadIdx.x;
    const float4 xv = *(const float4*)&x[(size_t)row * 1024 + tid * 4];
    float ss = xv.x * xv.x + xv.y * xv.y + xv.z * xv.z + xv.w * xv.w;
    #pragma unroll
    for (int off = 32; off > 0; off >>= 1) ss += __shfl_down(ss, off);
    if ((tid & 63) == 0) red[tid >> 6] = ss;
    __syncthreads();
    const float tot = red[0] + red[1] + red[2] + red[3];
    const float scale = rsqrtf(tot * (1.0f / 1024.0f) + 1e-6f);
    const float4 wv = *(const float4*)&w_rms[tid * 4];
    const u16 o0 = f2bf(xv.x * scale * wv.x), o1 = f2bf(xv.y * scale * wv.y);
    const u16 o2 = f2bf(xv.z * scale * wv.z), o3 = f2bf(xv.w * scale * wv.w);
    uint2 ov;
    ov.x = (u32)o0 | ((u32)o1 << 16);
    ov.y = (u32)o2 | ((u32)o3 << 16);
    *(uint2*)&xn[(size_t)row * 1024 + tid * 4] = ov;
  } else {
    const int pb = bid - 8192;               // 0..4127
    const int bx = pb % 129, by = pb / 129;  // bx 0..128, by 0..31
    const int tx = threadIdx.x & 31, ty = threadIdx.x >> 5;
    if (bx < 128) {
      const float* W; u16* Bt; int N, n0;
      if (bx < 96) { W = Wqkv; Bt = BtQkv; N = 3072; n0 = bx * 32; }
      else         { W = Wout; Bt = BtOut; N = 1024; n0 = (bx - 96) * 32; }
      const int k0 = by * 32;
      #pragma unroll
      for (int i = 0; i < 4; i++)
        tile[ty + i * 8][tx] = W[(size_t)(k0 + ty + i * 8) * N + n0 + tx];
      __syncthreads();
      #pragma unroll
      for (int i = 0; i < 4; i++)
        Bt[(size_t)(n0 + ty + i * 8) * 1024 + k0 + tx] = f2bf(tile[tx][ty + i * 8]);
    } else {
      const int tid = threadIdx.x;
      #pragma unroll
      for (int gg = 0; gg < 8; gg++) {
        const int g = by * 8 + gg;
        #pragma unroll
        for (int kk = 0; kk < 4; kk++) {
          const int k = kk * 256 + tid;
          u16 v = 0;
          if (g < 48) v = f2bf(wg[(size_t)k * 48 + g]);
          BtQkv[(size_t)(3072 + g) * 1024 + k] = v;
        }
      }
    }
  }
}

// =====================================================================================
// GEMM-QKV core (FROZEN R8 ensemble = best measured headline 242.7 us:
// 256x256, BK=64, 4-phase fused GITER, READ-then-STAGE order, WAITV4 ledger).
// gl2lds writes LINEAR; global SOURCE inverse-swizzled; ds_read applies swizzle
// (16B-chunk col ^= row&7).
// =====================================================================================

#define FENCE asm volatile("" ::: "memory")
#define SBAR  do { FENCE; __builtin_amdgcn_s_barrier(); FENCE; } while (0)
#define WAITV4 do { FENCE; asm volatile("s_waitcnt vmcnt(4)" ::: "memory"); } while (0)
#define WAITV2 do { FENCE; asm volatile("s_waitcnt vmcnt(2)" ::: "memory"); } while (0)
#define WAITV0 do { FENCE; asm volatile("s_waitcnt vmcnt(0)" ::: "memory"); } while (0)

#define STAGE_A(BUF, HALF, TILE) do { \
  const u16* s_ = Abase + (size_t)(TILE) * 64 + (size_t)(HALF) * 131072; \
  u16* l_ = &lds[((BUF) * 4 + (HALF)) * 8192 + tid * 8]; \
  gl2lds16(s_, l_); gl2lds16(s_ + 65536, l_ + 4096); \
} while (0)

#define STAGE_B(BUF, HALF, TILE) do { \
  const u16* s_ = Bbase + (size_t)(TILE) * 64 + (size_t)(HALF) * 131072; \
  u16* l_ = &lds[((BUF) * 4 + 2 + (HALF)) * 8192 + tid * 8]; \
  gl2lds16(s_, l_); gl2lds16(s_ + 65536, l_ + 4096); \
} while (0)

#define READ_A(ALDS, MH) do { \
  _Pragma("unroll") \
  for (int mi_ = 0; mi_ < 4; ++mi_) { \
    af[mi_][0] = *(const bf16x8*)((ALDS) + (MH) * 4096 + mi_ * 1024 + co0); \
    af[mi_][1] = *(const bf16x8*)((ALDS) + (MH) * 4096 + mi_ * 1024 + co1); \
  } \
} while (0)

#define READ_B(BLDS, NH) do { \
  _Pragma("unroll") \
  for (int ni_ = 0; ni_ < 2; ++ni_) { \
    bfr[NH][ni_][0] = *(const bf16x8*)((BLDS) + (NH) * 2048 + ni_ * 1024 + co0); \
    bfr[NH][ni_][1] = *(const bf16x8*)((BLDS) + (NH) * 2048 + ni_ * 1024 + co1); \
  } \
} while (0)

#define MFMA16(MH, NH) do { \
  __builtin_amdgcn_s_setprio(1); \
  _Pragma("unroll") \
  for (int mi_ = 0; mi_ < 4; ++mi_) { \
    _Pragma("unroll") \
    for (int ni_ = 0; ni_ < 2; ++ni_) { \
      acc[(MH)*4+mi_][(NH)*2+ni_] = __builtin_amdgcn_mfma_f32_16x16x32_bf16( \
          af[mi_][0], bfr[NH][ni_][0], acc[(MH)*4+mi_][(NH)*2+ni_], 0, 0, 0); \
      acc[(MH)*4+mi_][(NH)*2+ni_] = __builtin_amdgcn_mfma_f32_16x16x32_bf16( \
          af[mi_][1], bfr[NH][ni_][1], acc[(MH)*4+mi_][(NH)*2+ni_], 0, 0, 0); \
    } \
  } \
  __builtin_amdgcn_s_setprio(0); \
} while (0)

#define GITER4(T, FULL) do { \
  /*Q0 = P0+P1*/ \
  READ_A(aLds0, 0); READ_B(bLds0, 0); READ_B(bLds0, 1); \
  STAGE_A(1, 0, 2*(T)+1); STAGE_A(1, 1, 2*(T)+1); \
  SBAR; MFMA16(0, 0); MFMA16(0, 1); SBAR; \
  /*Q1 = P2+P3*/ \
  READ_A(aLds0, 1); \
  if (FULL) { STAGE_B(0, 0, 2*(T)+2); STAGE_B(0, 1, 2*(T)+2); } \
  SBAR; MFMA16(1, 0); MFMA16(1, 1); if (FULL) { WAITV4; } else { WAITV0; } SBAR; \
  /*Q2 = P4+P5*/ \
  READ_A(aLds1, 0); READ_B(bLds1, 0); READ_B(bLds1, 1); \
  if (FULL) { STAGE_A(0, 0, 2*(T)+2); STAGE_A(0, 1, 2*(T)+2); } \
  SBAR; MFMA16(0, 0); MFMA16(0, 1); SBAR; \
  /*Q3 = P6+P7*/ \
  READ_A(aLds1, 1); \
  if (FULL) { STAGE_B(1, 0, 2*(T)+3); STAGE_B(1, 1, 2*(T)+3); } \
  SBAR; MFMA16(1, 0); MFMA16(1, 1); if (FULL) { WAITV4; } SBAR; \
} while (0)

#define CORE_SETUP(AROWBASE, BCOLBASE) \
  const int tid = threadIdx.x; \
  const int lane = tid & 63, wave = tid >> 6; \
  const int q = lane >> 4, m16 = lane & 15; \
  const int wm = wave & 1, wn = wave >> 1; \
  const int sx = m16 & 7; \
  const int co0 = (q ^ sx) * 8; \
  const int co1 = ((4 + q) ^ sx) * 8; \
  const int r0 = tid >> 3, pc = tid & 7; \
  const int lcg = pc ^ (r0 & 7); \
  const u16* Abase = (AROWBASE) + (size_t)r0 * 1024 + lcg * 8; \
  const u16* Bbase = (BCOLBASE) + (size_t)r0 * 1024 + lcg * 8; \
  const u16* aLds0 = &lds[wm * 8192 + m16 * 64]; \
  const u16* aLds1 = aLds0 + 32768; \
  const u16* bLds0 = &lds[16384 + (wn >> 1) * 8192 + ((wn & 1) * 64 + m16) * 64]; \
  const u16* bLds1 = bLds0 + 32768; \
  bf16x8 af[4][2]; \
  bf16x8 bfr[2][2][2]; \
  f32x4 acc[8][4] = {};

#define CORE_RUN16() do { \
  STAGE_A(0, 0, 0); STAGE_A(0, 1, 0); STAGE_B(0, 0, 0); STAGE_B(0, 1, 0); \
  STAGE_B(1, 0, 1); STAGE_B(1, 1, 1); \
  WAITV4; SBAR; \
  _Pragma("unroll 1") \
  for (int t = 0; t < 7; ++t) GITER4(t, 1); \
  GITER4(7, 0); \
} while (0)

// ---------------- GEMM1: qkv + gates ----------------
__global__ __launch_bounds__(512, 2) void gemm_qkv(const u16* __restrict__ A, const u16* __restrict__ Bt,
                                                   u16* __restrict__ Qb, u16* __restrict__ Kb,
                                                   u16* __restrict__ Vb, float* __restrict__ gates) {
  __shared__ __attribute__((aligned(16))) u16 lds[65536];   // 128 KiB

  // bijective XCD swizzle: 416 blocks = 8 XCDs x 52 (bm-fastest)
  const int g = blockIdx.x;
  const int swz = (g & 7) * 52 + (g >> 3);
  const int bm = swz & 31, bn = swz >> 5;          // 32 row-tiles x 13 col-tiles
  const int rowBase = bm * 256, colBase = bn * 256;

  CORE_SETUP(A + (size_t)rowBase * 1024, Bt + (size_t)colBase * 1024);
  CORE_RUN16();

  // ---------------- epilogue ----------------
  const int rr = lane >> 2, co = (lane & 3) * 16;
  if (colBase < 3072) {
    const int which = colBase >> 10;
    u16* dstBase = (which == 0) ? Qb : ((which == 1) ? Kb : Vb);
    const int b = rowBase >> 11;
    const int h = ((colBase & 1023) >> 6) + wn;    // wave wn owns one 64-col head
    const int tRow0 = (rowBase & 2047) + wm * 128;
    u16* headBase = dstBase + ((size_t)(b * 16 + h)) * 2048 * 64;
    u16* scratch = lds + wave * 1024;   // 16 rows x 64 cols bf16 per wave
    #pragma unroll
    for (int mi = 0; mi < 8; ++mi) {
      #pragma unroll
      for (int bj = 0; bj < 4; ++bj)
        #pragma unroll
        for (int r = 0; r < 4; ++r)
          scratch[(q * 4 + r) * 64 + bj * 16 + m16] = f2bf(acc[mi][bj][r]);
      const uint4 d0 = *(const uint4*)&scratch[rr * 64 + co];
      const uint4 d1 = *(const uint4*)&scratch[rr * 64 + co + 8];
      u16* gp = headBase + (size_t)(tRow0 + mi * 16 + rr) * 64 + co;
      *(uint4*)gp = d0;
      *(uint4*)(gp + 8) = d1;
    }
  } else {
    // gates block: cols 3072..3327, only first 48 meaningful (waves wn==0 cover them)
    if (wn == 0) {
      #pragma unroll
      for (int ai = 0; ai < 8; ++ai)
        #pragma unroll
        for (int bj = 0; bj < 3; ++bj)
          #pragma unroll
          for (int r = 0; r < 4; ++r) {
            const int grow = rowBase + wm * 128 + ai * 16 + q * 4 + r;
            const int b = grow >> 11, tt = grow & 2047;
            const float v = acc[ai][bj][r];
            const float gg = 1.0f / (1.0f + __expf(-(15.0f * tanhf(v * (1.0f / 15.0f)))));
            gates[((size_t)bj * 64 + (b * 16 + m16)) * 2048 + tt] = gg;
          }
    }
  }
}

// =====================================================================================
// GEMM2 (R8 state): BM=128 x BN=256, BK=64, 512 threads, grid 256 = ONE full round.
// =====================================================================================

#define STAGE_AO(BUF, TILE) do { \
  const u16* s_ = Abase + (size_t)(TILE) * 64; \
  u16* l_ = &lds[(BUF) * 24576 + tid * 8]; \
  gl2lds16(s_, l_); gl2lds16(s_ + 65536, l_ + 4096); \
} while (0)

#define STAGE_BO(BUF, HALF, TILE) do { \
  const u16* s_ = Bbase + (size_t)(TILE) * 64 + (size_t)(HALF) * 131072; \
  u16* l_ = &lds[(BUF) * 24576 + 8192 + (HALF) * 8192 + tid * 8]; \
  gl2lds16(s_, l_); gl2lds16(s_ + 65536, l_ + 4096); \
} while (0)

#define READ_AO(ALDS) do { \
  _Pragma("unroll") \
  for (int mi_ = 0; mi_ < 4; ++mi_) { \
    af[mi_][0] = *(const bf16x8*)((ALDS) + mi_ * 1024 + co0); \
    af[mi_][1] = *(const bf16x8*)((ALDS) + mi_ * 1024 + co1); \
  } \
} while (0)

#define MFMA16O(NH) do { \
  __builtin_amdgcn_s_setprio(1); \
  _Pragma("unroll") \
  for (int mi_ = 0; mi_ < 4; ++mi_) { \
    _Pragma("unroll") \
    for (int ni_ = 0; ni_ < 2; ++ni_) { \
      acc[mi_][(NH)*2+ni_] = __builtin_amdgcn_mfma_f32_16x16x32_bf16( \
          af[mi_][0], bfr[NH][ni_][0], acc[mi_][(NH)*2+ni_], 0, 0, 0); \
      acc[mi_][(NH)*2+ni_] = __builtin_amdgcn_mfma_f32_16x16x32_bf16( \
          af[mi_][1], bfr[NH][ni_][1], acc[mi_][(NH)*2+ni_], 0, 0, 0); \
    } \
  } \
  __builtin_amdgcn_s_setprio(0); \
} while (0)

#define GITER_O(T, FULL) do { \
  /*Q0*/ READ_AO(aLds0); READ_B(bLds0, 0); \
         STAGE_BO(1, 0, 2*(T)+1); STAGE_BO(1, 1, 2*(T)+1); \
         SBAR; MFMA16O(0); SBAR; \
  /*Q1*/ READ_B(bLds0, 1); \
         if (FULL) STAGE_AO(0, 2*(T)+2); \
         SBAR; MFMA16O(1); if (FULL) { WAITV2; } else { WAITV0; } SBAR; \
  /*Q2*/ READ_AO(aLds1); READ_B(bLds1, 0); \
         if (FULL) { STAGE_BO(0, 0, 2*(T)+2); STAGE_BO(0, 1, 2*(T)+2); } \
         SBAR; MFMA16O(0); SBAR; \
  /*Q3*/ READ_B(bLds1, 1); \
         if (FULL) STAGE_AO(1, 2*(T)+3); \
         SBAR; MFMA16O(1); if (FULL) { WAITV2; } SBAR; \
} while (0)

__global__ __launch_bounds__(512, 2) void gemm_out(const u16* __restrict__ A, const u16* __restrict__ Bt,
                                                   const float* __restrict__ resid,
                                                   float* __restrict__ out) {
  __shared__ __attribute__((aligned(16))) u16 lds[49152];   // 96 KiB

  // 256 blocks = 8 XCDs x 32, bijective, bm-fastest
  const int g = blockIdx.x;
  const int swz = (g & 7) * 32 + (g >> 3);
  const int bm = swz & 63, bn = swz >> 6;          // 64 row-tiles x 4 col-tiles
  const int rowBase = bm * 128, colBase = bn * 256;

  const int tid = threadIdx.x;
  const int lane = tid & 63, wave = tid >> 6;
  const int q = lane >> 4, m16 = lane & 15;
  const int wm = wave & 1, wn = wave >> 1;
  const int sx = m16 & 7;
  const int co0 = (q ^ sx) * 8;
  const int co1 = ((4 + q) ^ sx) * 8;
  const int r0 = tid >> 3, pc = tid & 7;
  const int lcg = pc ^ (r0 & 7);
  const u16* Abase = A  + (size_t)rowBase * 1024 + (size_t)r0 * 1024 + lcg * 8;
  const u16* Bbase = Bt + (size_t)colBase * 1024 + (size_t)r0 * 1024 + lcg * 8;
  const u16* aLds0 = &lds[wm * 4096 + m16 * 64];
  const u16* aLds1 = aLds0 + 24576;
  const u16* bLds0 = &lds[8192 + (wn >> 1) * 8192 + ((wn & 1) * 64 + m16) * 64];
  const u16* bLds1 = bLds0 + 24576;
  bf16x8 af[4][2];
  bf16x8 bfr[2][2][2];
  f32x4 acc[4][4] = {};

  // prologue: buf0 full (tile0) + buf1.A (tile1); wait buf0 (vmcnt 8->2)
  STAGE_AO(0, 0); STAGE_BO(0, 0, 0); STAGE_BO(0, 1, 0);
  STAGE_AO(1, 1);
  WAITV2; SBAR;

  #pragma unroll 1
  for (int t = 0; t < 7; ++t) GITER_O(t, 1);
  GITER_O(7, 0);

  // epilogue: fp32 + residual, direct stores
  const int colW = colBase + wn * 64;
  #pragma unroll
  for (int mi = 0; mi < 4; ++mi)
    #pragma unroll
    for (int bj = 0; bj < 4; ++bj)
      #pragma unroll
      for (int r = 0; r < 4; ++r) {
        const int grow = rowBase + wm * 64 + mi * 16 + q * 4 + r;
        const int gcol = colW + bj * 16 + m16;
        const size_t idx = (size_t)grow * 1024 + gcol;
        out[idx] = acc[mi][bj][r] + resid[idx];
      }
}

// ---------------- pass A: la-scan + intra-chunk attention + chunk state increment M^T ----
// R13: decay-mask Wts (16 exp/thread) hoisted ABOVE the QK^T MFMA phase — it depends
// only on laS/iS (final after barrier 1), so it now overlaps the Q/K/V load latency
// and the MFMA phase (VALU and MFMA are separate pipes) instead of serializing after.
__global__ __launch_bounds__(256) void passA_k(const u16* __restrict__ Qb, const u16* __restrict__ Kb,
                                               const u16* __restrict__ Vb,
                                               const float* __restrict__ gates,
                                               float* __restrict__ la,
                                               u16* __restrict__ Mbuf, u16* __restrict__ hseq) {
  __shared__ u16 Ql[64][72], Kl[64][72], KTl[64][72], VTl[64][72], Pl[64][72];
  __shared__ float laS[64], iS[64];
  const int tid = threadIdx.x;
  const int bh = blockIdx.x >> 5, c = blockIdx.x & 31;
  const int lane = tid & 63, w = tid >> 6;
  const int q = lane >> 4, m16 = lane & 15;
  const size_t base = ((size_t)bh * 2048 + c * 64) * 64;
  const int toff = c * 64;   // time offset within the (bh) chain

  // wave 0: chunk-local cumulative log-f scan (fused la_k)
  if (tid < 64) {
    float lg = __logf(gates[(size_t)(64 + bh) * 2048 + toff + tid]);  // f-gate
    #pragma unroll
    for (int off = 1; off < 64; off <<= 1) {
      const float y = __shfl_up(lg, off);
      if (tid >= off) lg += y;
    }
    laS[tid] = lg;
    iS[tid] = gates[(size_t)bh * 2048 + toff + tid];  // i-gate
    la[(size_t)bh * 2048 + toff + tid] = lg;          // for passB/passC
  }
  __syncthreads();

  {
    const int s = tid >> 2, db = (tid & 3) * 16;
    const float wk = __expf(laS[63] - laS[s]) * iS[s];
    const uint4 q0 = *(const uint4*)&Qb[base + s * 64 + db];
    const uint4 q1 = *(const uint4*)&Qb[base + s * 64 + db + 8];
    *(uint4*)&Ql[s][db] = q0;
    *(uint4*)&Ql[s][db + 8] = q1;
    const uint4 k0 = *(const uint4*)&Kb[base + s * 64 + db];
    const uint4 k1 = *(const uint4*)&Kb[base + s * 64 + db + 8];
    *(uint4*)&Kl[s][db] = k0;
    *(uint4*)&Kl[s][db + 8] = k1;
    u16 ktmp[16];
    *(uint4*)&ktmp[0] = k0;
    *(uint4*)&ktmp[8] = k1;
    #pragma unroll
    for (int j = 0; j < 16; j++) KTl[db + j][s] = f2bf(wk * bf2f(ktmp[j]));
    const uint4 v0 = *(const uint4*)&Vb[base + s * 64 + db];
    const uint4 v1 = *(const uint4*)&Vb[base + s * 64 + db + 8];
    u16 vtmp[16];
    *(uint4*)&vtmp[0] = v0;
    *(uint4*)&vtmp[8] = v1;
    #pragma unroll
    for (int j = 0; j < 16; j++) VTl[db + j][s] = vtmp[j];
  }

  // hoisted decay-mask weights (laS/iS final since barrier 1; overlaps loads & MFMA)
  float Wts[4][4];
  #pragma unroll
  for (int ni = 0; ni < 4; ni++)
    #pragma unroll
    for (int r = 0; r < 4; r++) {
      const int tt = w * 16 + q * 4 + r, ss = ni * 16 + m16;
      Wts[ni][r] = (ss <= tt) ? __expf(laS[tt] - laS[ss]) * iS[ss] : 0.0f;
    }
  __syncthreads();

  // P = (Q K^T) * decay-mask
  f32x4 pacc[4] = {};
  #pragma unroll
  for (int ks = 0; ks < 2; ks++) {
    const bf16x8 aq = *(const bf16x8*)&Ql[w * 16 + m16][ks * 32 + q * 8];
    #pragma unroll
    for (int ni = 0; ni < 4; ni++) {
      const bf16x8 bk = *(const bf16x8*)&Kl[ni * 16 + m16][ks * 32 + q * 8];
      pacc[ni] = __builtin_amdgcn_mfma_f32_16x16x32_bf16(aq, bk, pacc[ni], 0, 0, 0);
    }
  }
  #pragma unroll
  for (int ni = 0; ni < 4; ni++)
    #pragma unroll
    for (int r = 0; r < 4; r++) {
      const int tt = w * 16 + q * 4 + r, ss = ni * 16 + m16;
      Pl[tt][ss] = f2bf(pacc[ni][r] * Wts[ni][r]);
    }
  __syncthreads();

  // h_intra = P @ V ; M^T via mfma(bv, ak) -> C[e][d]
  f32x4 hacc[4] = {}, macc[4] = {};
  #pragma unroll
  for (int ks = 0; ks < 2; ks++) {
    const bf16x8 ap = *(const bf16x8*)&Pl[w * 16 + m16][ks * 32 + q * 8];
    const bf16x8 av = *(const bf16x8*)&VTl[w * 16 + m16][ks * 32 + q * 8];
    #pragma unroll
    for (int ni = 0; ni < 4; ni++) {
      const bf16x8 bv = *(const bf16x8*)&VTl[ni * 16 + m16][ks * 32 + q * 8];
      const bf16x8 bk = *(const bf16x8*)&KTl[ni * 16 + m16][ks * 32 + q * 8];
      hacc[ni] = __builtin_amdgcn_mfma_f32_16x16x32_bf16(ap, bv, hacc[ni], 0, 0, 0);
      macc[ni] = __builtin_amdgcn_mfma_f32_16x16x32_bf16(av, bk, macc[ni], 0, 0, 0);
    }
  }

  // vectorized epilogue: stage into Pl (h) and Kl (M), then uint4 stores.
  __syncthreads();   // all Pl (ap operand) reads complete before overwrite
  #pragma unroll
  for (int ni = 0; ni < 4; ni++)
    #pragma unroll
    for (int r = 0; r < 4; r++) {
      const int tt = w * 16 + q * 4 + r, e = ni * 16 + m16;
      Pl[tt][e] = f2bf(hacc[ni][r]);
      Kl[tt][e] = f2bf(macc[ni][r]);
    }
  __syncthreads();
  {
    const int s = tid >> 2, db = (tid & 3) * 16;
    const int b = bh >> 4, h = bh & 15;
    u16* hp = &hseq[((size_t)b * 2048 + c * 64 + s) * 1024 + h * 64 + db];
    *(uint4*)hp       = *(const uint4*)&Pl[s][db];
    *(uint4*)(hp + 8) = *(const uint4*)&Pl[s][db + 8];
    u16* mp = &Mbuf[(((size_t)bh * 32 + c) * 64 + s) * 64 + db];
    *(uint4*)mp       = *(const uint4*)&Kl[s][db];
    *(uint4*)(mp + 8) = *(const uint4*)&Kl[s][db + 8];
  }
}

// ---------------- pass B: inter-chunk state scan (in place, bf16: M^T[c] -> S_prev^T[c]) ----------------
__global__ __launch_bounds__(256) void passB_k(u16* __restrict__ Mbuf,
                                               const float* __restrict__ hidden,
                                               const float* __restrict__ la) {
  const int bh = blockIdx.x >> 4;
  const int e = (blockIdx.x & 15) * 256 + threadIdx.x;   // flat idx in 4096 = [e][d] (transposed)
  __shared__ float Gs[32];
  if (threadIdx.x < 32)
    Gs[threadIdx.x] = __expf(la[(size_t)bh * 2048 + threadIdx.x * 64 + 63]);
  __syncthreads();
  const int eRow = e >> 6, dCol = e & 63;
  float st = hidden[(size_t)bh * 4096 + dCol * 64 + eRow];
  u16* M = &Mbuf[(size_t)bh * 32 * 4096 + e];
  float m_next = bf2f(M[0]);
  #pragma unroll 4
  for (int c = 0; c < 32; c++) {
    const float m_cur = m_next;
    if (c < 31) m_next = bf2f(M[(size_t)(c + 1) * 4096]);
    M[(size_t)c * 4096] = f2bf(st);
    st = Gs[c] * st + m_cur;
  }
}

// ---------------- pass C: h = o * (h_intra + a_t * q^T S_prev) ----------------
// R13: a_t/o hoisted above the MFMA phase (available after the single barrier) so the
// exp overlaps ds_reads/MFMA instead of serializing before the RMW.
__global__ __launch_bounds__(256) void passC_k(const u16* __restrict__ Qb,
                                               const u16* __restrict__ SprevT,
                                               const float* __restrict__ la,
                                               const float* __restrict__ gates,
                                               u16* __restrict__ hseq) {
  __shared__ u16 aQl[64][72], STl[64][72];
  __shared__ float hstage[64][68];   // f32 staging; stride 272 B = 17x16 B (aligned)
  __shared__ float laS[64], oS[64];
  const int tid = threadIdx.x;
  const int bh = blockIdx.x >> 5, c = blockIdx.x & 31;
  const int lane = tid & 63, w = tid >> 6;
  const int q = lane >> 4, m16 = lane & 15;
  const size_t base = ((size_t)bh * 2048 + c * 64) * 64;
  const int toff = c * 64;
  if (tid < 64) {
    laS[tid] = la[(size_t)bh * 2048 + toff + tid];
    oS[tid] = gates[(size_t)(128 + bh) * 2048 + toff + tid];  // o-gate
  }
  {
    const int s = tid >> 2, db = (tid & 3) * 16;
    *(uint4*)&aQl[s][db]     = *(const uint4*)&Qb[base + s * 64 + db];
    *(uint4*)&aQl[s][db + 8] = *(const uint4*)&Qb[base + s * 64 + db + 8];
    const u16* SpT = &SprevT[((size_t)bh * 32 + c) * 4096];
    *(uint4*)&STl[s][db]     = *(const uint4*)&SpT[s * 64 + db];
    *(uint4*)&STl[s][db + 8] = *(const uint4*)&SpT[s * 64 + db + 8];
  }
  __syncthreads();
  // hoisted epilogue scalars (overlap exp with ds_reads/MFMA below)
  const int sE = tid >> 2, dbE = (tid & 3) * 16;
  const float a_t = __expf(laS[sE]);
  const float o = oS[sE];
  f32x4 acc[4] = {};
  #pragma unroll
  for (int ks = 0; ks < 2; ks++) {
    const bf16x8 a = *(const bf16x8*)&aQl[w * 16 + m16][ks * 32 + q * 8];
    #pragma unroll
    for (int ni = 0; ni < 4; ni++) {
      const bf16x8 bb = *(const bf16x8*)&STl[ni * 16 + m16][ks * 32 + q * 8];
      acc[ni] = __builtin_amdgcn_mfma_f32_16x16x32_bf16(a, bb, acc[ni], 0, 0, 0);
    }
  }
  // stage acc (f32), then vectorized RMW of hseq with row-uniform a_t, o
  #pragma unroll
  for (int ni = 0; ni < 4; ni++)
    #pragma unroll
    for (int r = 0; r < 4; r++)
      hstage[w * 16 + q * 4 + r][ni * 16 + m16] = acc[ni][r];
  __syncthreads();
  {
    const int b = bh >> 4, h = bh & 15;
    u16* hp = &hseq[((size_t)b * 2048 + c * 64 + sE) * 1024 + h * 64 + dbE];
    uint4 h0 = *(const uint4*)hp, h1 = *(const uint4*)(hp + 8);
    u16 hv[16];
    *(uint4*)&hv[0] = h0;
    *(uint4*)&hv[8] = h1;
    float sv[16];
    *(float4*)&sv[0]  = *(const float4*)&hstage[sE][dbE];
    *(float4*)&sv[4]  = *(const float4*)&hstage[sE][dbE + 4];
    *(float4*)&sv[8]  = *(const float4*)&hstage[sE][dbE + 8];
    *(float4*)&sv[12] = *(const float4*)&hstage[sE][dbE + 12];
    u16 ov[16];
    #pragma unroll
    for (int j = 0; j < 16; j++)
      ov[j] = f2bf(o * (bf2f(hv[j]) + a_t * sv[j]));
    *(uint4*)hp       = *(const uint4*)&ov[0];
    *(uint4*)(hp + 8) = *(const uint4*)&ov[8];
  }
}

extern "C" void kernel_launch(void* const* d_in, const int* in_sizes, int n_in,
                              void* d_out, int out_size, void* d_ws, size_t ws_size,
                              hipStream_t stream) {
  (void)in_sizes; (void)n_in; (void)out_size; (void)ws_size;
  const float* x      = (const float*)d_in[0];
  const float* hidden = (const float*)d_in[1];
  const float* w_rms  = (const float*)d_in[2];
  const float* w_qkv  = (const float*)d_in[3];
  const float* w_gate = (const float*)d_in[4];
  const float* w_out  = (const float*)d_in[5];
  float* out = (float*)d_out;

  char* p = (char*)d_ws;
  u16* wqkvT = (u16*)p;  p += (size_t)N1 * 1024 * 2;        // 6.8 MB
  u16* woutT = (u16*)p;  p += (size_t)1024 * 1024 * 2;      // 2.1 MB
  u16* xn    = (u16*)p;  p += (size_t)ROWS * 1024 * 2;      // 16.8 MB
  u16* Qb    = (u16*)p;  p += (size_t)BH * 2048 * 64 * 2;   // 16.8 MB
  u16* Kb    = (u16*)p;  p += (size_t)BH * 2048 * 64 * 2;
  u16* Vb    = (u16*)p;  p += (size_t)BH * 2048 * 64 * 2;
  float* gates = (float*)p; p += (size_t)3 * BH * 2048 * 4; // 1.6 MB
  float* la    = (float*)p; p += (size_t)BH * 2048 * 4;     // 0.5 MB
  u16* Mbuf  = (u16*)p;  p += (size_t)BH * NC * 4096 * 2;   // 16.8 MB (bf16, transposed)
  u16* hseq  = (u16*)p;  p += (size_t)ROWS * 1024 * 2;      // 16.8 MB

  prep_all<<<12320, 256, 0, stream>>>(x, w_rms, xn, w_qkv, w_out, w_gate, wqkvT, woutT);
  gemm_qkv<<<416, 512, 0, stream>>>(xn, wqkvT, Qb, Kb, Vb, gates);
  passA_k<<<BH * NC, 256, 0, stream>>>(Qb, Kb, Vb, gates, la, Mbuf, hseq);
  passB_k<<<BH * 16, 256, 0, stream>>>(Mbuf, hidden, la);
  passC_k<<<BH * NC, 256, 0, stream>>>(Qb, Mbuf, la, gates, hseq);
  gemm_out<<<256, 512, 0, stream>>>(hseq, woutT, x, out);
}

// Round 14
// 238.756 us; speedup vs baseline: 1.0826x; 1.0826x over previous
//
#include <hip/hip_runtime.h>
#include <math.h>

typedef unsigned short u16;
typedef unsigned int   u32;
typedef __bf16 bf16x8 __attribute__((ext_vector_type(8)));
typedef float  f32x4  __attribute__((ext_vector_type(4)));

// B=4 S=2048 D=1024 H=16 Dh=64 -> BH=64 chains, 32 chunks of 64
#define NBATCH 4
#define SEQ    2048
#define DIM    1024
#define NH     16
#define BH     64
#define NC     32
#define ROWS   8192
#define N1     3328   /* 3072 qkv cols + 48 gate cols padded to 256 for 256-wide tiles */

__device__ __forceinline__ u16 f2bf(float f) {
  u32 u = __builtin_bit_cast(u32, f);
  u32 r = u + 0x7fffu + ((u >> 16) & 1u);
  return (u16)(r >> 16);
}
__device__ __forceinline__ float bf2f(u16 h) {
  return __builtin_bit_cast(float, (u32)h << 16);
}

// async global->LDS, 16B per lane; LDS dest = wave-uniform base + lane*16
__device__ __forceinline__ void gl2lds16(const u16* g, u16* l) {
  __builtin_amdgcn_global_load_lds(
      (const __attribute__((address_space(1))) u32*)g,
      (__attribute__((address_space(3))) u32*)l, 16, 0, 0);
}

// ---------------- fused prep: rmsnorm (blocks 0..8191) + weight transposes/gate fill ----
// grid 8192 + 129*32 = 12320 blocks, 256 threads.
__global__ __launch_bounds__(256) void prep_all(const float* __restrict__ x,
                                                const float* __restrict__ w_rms,
                                                u16* __restrict__ xn,
                                                const float* __restrict__ Wqkv,
                                                const float* __restrict__ Wout,
                                                const float* __restrict__ wg,
                                                u16* __restrict__ BtQkv, u16* __restrict__ BtOut) {
  __shared__ float tile[32][33];
  __shared__ float red[4];
  const int bid = blockIdx.x;
  if (bid < 8192) {
    // ---- RMSNorm row ----
    const int row = bid, tid = threadIdx.x;
    const float4 xv = *(const float4*)&x[(size_t)row * 1024 + tid * 4];
    float ss = xv.x * xv.x + xv.y * xv.y + xv.z * xv.z + xv.w * xv.w;
    #pragma unroll
    for (int off = 32; off > 0; off >>= 1) ss += __shfl_down(ss, off);
    if ((tid & 63) == 0) red[tid >> 6] = ss;
    __syncthreads();
    const float tot = red[0] + red[1] + red[2] + red[3];
    const float scale = rsqrtf(tot * (1.0f / 1024.0f) + 1e-6f);
    const float4 wv = *(const float4*)&w_rms[tid * 4];
    const u16 o0 = f2bf(xv.x * scale * wv.x), o1 = f2bf(xv.y * scale * wv.y);
    const u16 o2 = f2bf(xv.z * scale * wv.z), o3 = f2bf(xv.w * scale * wv.w);
    uint2 ov;
    ov.x = (u32)o0 | ((u32)o1 << 16);
    ov.y = (u32)o2 | ((u32)o3 << 16);
    *(uint2*)&xn[(size_t)row * 1024 + tid * 4] = ov;
  } else {
    const int pb = bid - 8192;               // 0..4127
    const int bx = pb % 129, by = pb / 129;  // bx 0..128, by 0..31
    const int tx = threadIdx.x & 31, ty = threadIdx.x >> 5;
    if (bx < 128) {
      const float* W; u16* Bt; int N, n0;
      if (bx < 96) { W = Wqkv; Bt = BtQkv; N = 3072; n0 = bx * 32; }
      else         { W = Wout; Bt = BtOut; N = 1024; n0 = (bx - 96) * 32; }
      const int k0 = by * 32;
      #pragma unroll
      for (int i = 0; i < 4; i++)
        tile[ty + i * 8][tx] = W[(size_t)(k0 + ty + i * 8) * N + n0 + tx];
      __syncthreads();
      #pragma unroll
      for (int i = 0; i < 4; i++)
        Bt[(size_t)(n0 + ty + i * 8) * 1024 + k0 + tx] = f2bf(tile[tx][ty + i * 8]);
    } else {
      const int tid = threadIdx.x;
      #pragma unroll
      for (int gg = 0; gg < 8; gg++) {
        const int g = by * 8 + gg;
        #pragma unroll
        for (int kk = 0; kk < 4; kk++) {
          const int k = kk * 256 + tid;
          u16 v = 0;
          if (g < 48) v = f2bf(wg[(size_t)k * 48 + g]);
          BtQkv[(size_t)(3072 + g) * 1024 + k] = v;
        }
      }
    }
  }
}

// =====================================================================================
// GEMM-QKV core (FINAL = R8 ensemble, best measured headline 242.7 us:
// 256x256, BK=64, 4-phase fused GITER, READ-then-STAGE order, WAITV4 ledger).
// gl2lds writes LINEAR; global SOURCE inverse-swizzled; ds_read applies swizzle
// (16B-chunk col ^= row&7).
// =====================================================================================

#define FENCE asm volatile("" ::: "memory")
#define SBAR  do { FENCE; __builtin_amdgcn_s_barrier(); FENCE; } while (0)
#define WAITV4 do { FENCE; asm volatile("s_waitcnt vmcnt(4)" ::: "memory"); } while (0)
#define WAITV2 do { FENCE; asm volatile("s_waitcnt vmcnt(2)" ::: "memory"); } while (0)
#define WAITV0 do { FENCE; asm volatile("s_waitcnt vmcnt(0)" ::: "memory"); } while (0)

#define STAGE_A(BUF, HALF, TILE) do { \
  const u16* s_ = Abase + (size_t)(TILE) * 64 + (size_t)(HALF) * 131072; \
  u16* l_ = &lds[((BUF) * 4 + (HALF)) * 8192 + tid * 8]; \
  gl2lds16(s_, l_); gl2lds16(s_ + 65536, l_ + 4096); \
} while (0)

#define STAGE_B(BUF, HALF, TILE) do { \
  const u16* s_ = Bbase + (size_t)(TILE) * 64 + (size_t)(HALF) * 131072; \
  u16* l_ = &lds[((BUF) * 4 + 2 + (HALF)) * 8192 + tid * 8]; \
  gl2lds16(s_, l_); gl2lds16(s_ + 65536, l_ + 4096); \
} while (0)

#define READ_A(ALDS, MH) do { \
  _Pragma("unroll") \
  for (int mi_ = 0; mi_ < 4; ++mi_) { \
    af[mi_][0] = *(const bf16x8*)((ALDS) + (MH) * 4096 + mi_ * 1024 + co0); \
    af[mi_][1] = *(const bf16x8*)((ALDS) + (MH) * 4096 + mi_ * 1024 + co1); \
  } \
} while (0)

#define READ_B(BLDS, NH) do { \
  _Pragma("unroll") \
  for (int ni_ = 0; ni_ < 2; ++ni_) { \
    bfr[NH][ni_][0] = *(const bf16x8*)((BLDS) + (NH) * 2048 + ni_ * 1024 + co0); \
    bfr[NH][ni_][1] = *(const bf16x8*)((BLDS) + (NH) * 2048 + ni_ * 1024 + co1); \
  } \
} while (0)

#define MFMA16(MH, NH) do { \
  __builtin_amdgcn_s_setprio(1); \
  _Pragma("unroll") \
  for (int mi_ = 0; mi_ < 4; ++mi_) { \
    _Pragma("unroll") \
    for (int ni_ = 0; ni_ < 2; ++ni_) { \
      acc[(MH)*4+mi_][(NH)*2+ni_] = __builtin_amdgcn_mfma_f32_16x16x32_bf16( \
          af[mi_][0], bfr[NH][ni_][0], acc[(MH)*4+mi_][(NH)*2+ni_], 0, 0, 0); \
      acc[(MH)*4+mi_][(NH)*2+ni_] = __builtin_amdgcn_mfma_f32_16x16x32_bf16( \
          af[mi_][1], bfr[NH][ni_][1], acc[(MH)*4+mi_][(NH)*2+ni_], 0, 0, 0); \
    } \
  } \
  __builtin_amdgcn_s_setprio(0); \
} while (0)

#define GITER4(T, FULL) do { \
  /*Q0 = P0+P1*/ \
  READ_A(aLds0, 0); READ_B(bLds0, 0); READ_B(bLds0, 1); \
  STAGE_A(1, 0, 2*(T)+1); STAGE_A(1, 1, 2*(T)+1); \
  SBAR; MFMA16(0, 0); MFMA16(0, 1); SBAR; \
  /*Q1 = P2+P3*/ \
  READ_A(aLds0, 1); \
  if (FULL) { STAGE_B(0, 0, 2*(T)+2); STAGE_B(0, 1, 2*(T)+2); } \
  SBAR; MFMA16(1, 0); MFMA16(1, 1); if (FULL) { WAITV4; } else { WAITV0; } SBAR; \
  /*Q2 = P4+P5*/ \
  READ_A(aLds1, 0); READ_B(bLds1, 0); READ_B(bLds1, 1); \
  if (FULL) { STAGE_A(0, 0, 2*(T)+2); STAGE_A(0, 1, 2*(T)+2); } \
  SBAR; MFMA16(0, 0); MFMA16(0, 1); SBAR; \
  /*Q3 = P6+P7*/ \
  READ_A(aLds1, 1); \
  if (FULL) { STAGE_B(1, 0, 2*(T)+3); STAGE_B(1, 1, 2*(T)+3); } \
  SBAR; MFMA16(1, 0); MFMA16(1, 1); if (FULL) { WAITV4; } SBAR; \
} while (0)

#define CORE_SETUP(AROWBASE, BCOLBASE) \
  const int tid = threadIdx.x; \
  const int lane = tid & 63, wave = tid >> 6; \
  const int q = lane >> 4, m16 = lane & 15; \
  const int wm = wave & 1, wn = wave >> 1; \
  const int sx = m16 & 7; \
  const int co0 = (q ^ sx) * 8; \
  const int co1 = ((4 + q) ^ sx) * 8; \
  const int r0 = tid >> 3, pc = tid & 7; \
  const int lcg = pc ^ (r0 & 7); \
  const u16* Abase = (AROWBASE) + (size_t)r0 * 1024 + lcg * 8; \
  const u16* Bbase = (BCOLBASE) + (size_t)r0 * 1024 + lcg * 8; \
  const u16* aLds0 = &lds[wm * 8192 + m16 * 64]; \
  const u16* aLds1 = aLds0 + 32768; \
  const u16* bLds0 = &lds[16384 + (wn >> 1) * 8192 + ((wn & 1) * 64 + m16) * 64]; \
  const u16* bLds1 = bLds0 + 32768; \
  bf16x8 af[4][2]; \
  bf16x8 bfr[2][2][2]; \
  f32x4 acc[8][4] = {};

#define CORE_RUN16() do { \
  STAGE_A(0, 0, 0); STAGE_A(0, 1, 0); STAGE_B(0, 0, 0); STAGE_B(0, 1, 0); \
  STAGE_B(1, 0, 1); STAGE_B(1, 1, 1); \
  WAITV4; SBAR; \
  _Pragma("unroll 1") \
  for (int t = 0; t < 7; ++t) GITER4(t, 1); \
  GITER4(7, 0); \
} while (0)

// ---------------- GEMM1: qkv + gates ----------------
__global__ __launch_bounds__(512, 2) void gemm_qkv(const u16* __restrict__ A, const u16* __restrict__ Bt,
                                                   u16* __restrict__ Qb, u16* __restrict__ Kb,
                                                   u16* __restrict__ Vb, float* __restrict__ gates) {
  __shared__ __attribute__((aligned(16))) u16 lds[65536];   // 128 KiB

  // bijective XCD swizzle: 416 blocks = 8 XCDs x 52 (bm-fastest)
  const int g = blockIdx.x;
  const int swz = (g & 7) * 52 + (g >> 3);
  const int bm = swz & 31, bn = swz >> 5;          // 32 row-tiles x 13 col-tiles
  const int rowBase = bm * 256, colBase = bn * 256;

  CORE_SETUP(A + (size_t)rowBase * 1024, Bt + (size_t)colBase * 1024);
  CORE_RUN16();

  // ---------------- epilogue ----------------
  const int rr = lane >> 2, co = (lane & 3) * 16;
  if (colBase < 3072) {
    const int which = colBase >> 10;
    u16* dstBase = (which == 0) ? Qb : ((which == 1) ? Kb : Vb);
    const int b = rowBase >> 11;
    const int h = ((colBase & 1023) >> 6) + wn;    // wave wn owns one 64-col head
    const int tRow0 = (rowBase & 2047) + wm * 128;
    u16* headBase = dstBase + ((size_t)(b * 16 + h)) * 2048 * 64;
    u16* scratch = lds + wave * 1024;   // 16 rows x 64 cols bf16 per wave
    #pragma unroll
    for (int mi = 0; mi < 8; ++mi) {
      #pragma unroll
      for (int bj = 0; bj < 4; ++bj)
        #pragma unroll
        for (int r = 0; r < 4; ++r)
          scratch[(q * 4 + r) * 64 + bj * 16 + m16] = f2bf(acc[mi][bj][r]);
      const uint4 d0 = *(const uint4*)&scratch[rr * 64 + co];
      const uint4 d1 = *(const uint4*)&scratch[rr * 64 + co + 8];
      u16* gp = headBase + (size_t)(tRow0 + mi * 16 + rr) * 64 + co;
      *(uint4*)gp = d0;
      *(uint4*)(gp + 8) = d1;
    }
  } else {
    // gates block: cols 3072..3327, only first 48 meaningful (waves wn==0 cover them)
    if (wn == 0) {
      #pragma unroll
      for (int ai = 0; ai < 8; ++ai)
        #pragma unroll
        for (int bj = 0; bj < 3; ++bj)
          #pragma unroll
          for (int r = 0; r < 4; ++r) {
            const int grow = rowBase + wm * 128 + ai * 16 + q * 4 + r;
            const int b = grow >> 11, tt = grow & 2047;
            const float v = acc[ai][bj][r];
            const float gg = 1.0f / (1.0f + __expf(-(15.0f * tanhf(v * (1.0f / 15.0f)))));
            gates[((size_t)bj * 64 + (b * 16 + m16)) * 2048 + tt] = gg;
          }
    }
  }
}

// =====================================================================================
// GEMM2 (R8 state): BM=128 x BN=256, BK=64, 512 threads, grid 256 = ONE full round.
// =====================================================================================

#define STAGE_AO(BUF, TILE) do { \
  const u16* s_ = Abase + (size_t)(TILE) * 64; \
  u16* l_ = &lds[(BUF) * 24576 + tid * 8]; \
  gl2lds16(s_, l_); gl2lds16(s_ + 65536, l_ + 4096); \
} while (0)

#define STAGE_BO(BUF, HALF, TILE) do { \
  const u16* s_ = Bbase + (size_t)(TILE) * 64 + (size_t)(HALF) * 131072; \
  u16* l_ = &lds[(BUF) * 24576 + 8192 + (HALF) * 8192 + tid * 8]; \
  gl2lds16(s_, l_); gl2lds16(s_ + 65536, l_ + 4096); \
} while (0)

#define READ_AO(ALDS) do { \
  _Pragma("unroll") \
  for (int mi_ = 0; mi_ < 4; ++mi_) { \
    af[mi_][0] = *(const bf16x8*)((ALDS) + mi_ * 1024 + co0); \
    af[mi_][1] = *(const bf16x8*)((ALDS) + mi_ * 1024 + co1); \
  } \
} while (0)

#define MFMA16O(NH) do { \
  __builtin_amdgcn_s_setprio(1); \
  _Pragma("unroll") \
  for (int mi_ = 0; mi_ < 4; ++mi_) { \
    _Pragma("unroll") \
    for (int ni_ = 0; ni_ < 2; ++ni_) { \
      acc[mi_][(NH)*2+ni_] = __builtin_amdgcn_mfma_f32_16x16x32_bf16( \
          af[mi_][0], bfr[NH][ni_][0], acc[mi_][(NH)*2+ni_], 0, 0, 0); \
      acc[mi_][(NH)*2+ni_] = __builtin_amdgcn_mfma_f32_16x16x32_bf16( \
          af[mi_][1], bfr[NH][ni_][1], acc[mi_][(NH)*2+ni_], 0, 0, 0); \
    } \
  } \
  __builtin_amdgcn_s_setprio(0); \
} while (0)

#define GITER_O(T, FULL) do { \
  /*Q0*/ READ_AO(aLds0); READ_B(bLds0, 0); \
         STAGE_BO(1, 0, 2*(T)+1); STAGE_BO(1, 1, 2*(T)+1); \
         SBAR; MFMA16O(0); SBAR; \
  /*Q1*/ READ_B(bLds0, 1); \
         if (FULL) STAGE_AO(0, 2*(T)+2); \
         SBAR; MFMA16O(1); if (FULL) { WAITV2; } else { WAITV0; } SBAR; \
  /*Q2*/ READ_AO(aLds1); READ_B(bLds1, 0); \
         if (FULL) { STAGE_BO(0, 0, 2*(T)+2); STAGE_BO(0, 1, 2*(T)+2); } \
         SBAR; MFMA16O(0); SBAR; \
  /*Q3*/ READ_B(bLds1, 1); \
         if (FULL) STAGE_AO(1, 2*(T)+3); \
         SBAR; MFMA16O(1); if (FULL) { WAITV2; } SBAR; \
} while (0)

__global__ __launch_bounds__(512, 2) void gemm_out(const u16* __restrict__ A, const u16* __restrict__ Bt,
                                                   const float* __restrict__ resid,
                                                   float* __restrict__ out) {
  __shared__ __attribute__((aligned(16))) u16 lds[49152];   // 96 KiB

  // 256 blocks = 8 XCDs x 32, bijective, bm-fastest
  const int g = blockIdx.x;
  const int swz = (g & 7) * 32 + (g >> 3);
  const int bm = swz & 63, bn = swz >> 6;          // 64 row-tiles x 4 col-tiles
  const int rowBase = bm * 128, colBase = bn * 256;

  const int tid = threadIdx.x;
  const int lane = tid & 63, wave = tid >> 6;
  const int q = lane >> 4, m16 = lane & 15;
  const int wm = wave & 1, wn = wave >> 1;
  const int sx = m16 & 7;
  const int co0 = (q ^ sx) * 8;
  const int co1 = ((4 + q) ^ sx) * 8;
  const int r0 = tid >> 3, pc = tid & 7;
  const int lcg = pc ^ (r0 & 7);
  const u16* Abase = A  + (size_t)rowBase * 1024 + (size_t)r0 * 1024 + lcg * 8;
  const u16* Bbase = Bt + (size_t)colBase * 1024 + (size_t)r0 * 1024 + lcg * 8;
  const u16* aLds0 = &lds[wm * 4096 + m16 * 64];
  const u16* aLds1 = aLds0 + 24576;
  const u16* bLds0 = &lds[8192 + (wn >> 1) * 8192 + ((wn & 1) * 64 + m16) * 64];
  const u16* bLds1 = bLds0 + 24576;
  bf16x8 af[4][2];
  bf16x8 bfr[2][2][2];
  f32x4 acc[4][4] = {};

  // prologue: buf0 full (tile0) + buf1.A (tile1); wait buf0 (vmcnt 8->2)
  STAGE_AO(0, 0); STAGE_BO(0, 0, 0); STAGE_BO(0, 1, 0);
  STAGE_AO(1, 1);
  WAITV2; SBAR;

  #pragma unroll 1
  for (int t = 0; t < 7; ++t) GITER_O(t, 1);
  GITER_O(7, 0);

  // epilogue: fp32 + residual, direct stores
  const int colW = colBase + wn * 64;
  #pragma unroll
  for (int mi = 0; mi < 4; ++mi)
    #pragma unroll
    for (int bj = 0; bj < 4; ++bj)
      #pragma unroll
      for (int r = 0; r < 4; ++r) {
        const int grow = rowBase + wm * 64 + mi * 16 + q * 4 + r;
        const int gcol = colW + bj * 16 + m16;
        const size_t idx = (size_t)grow * 1024 + gcol;
        out[idx] = acc[mi][bj][r] + resid[idx];
      }
}

// ---------------- pass A: la-scan + intra-chunk attention + chunk state increment M^T ----------------
__global__ __launch_bounds__(256) void passA_k(const u16* __restrict__ Qb, const u16* __restrict__ Kb,
                                               const u16* __restrict__ Vb,
                                               const float* __restrict__ gates,
                                               float* __restrict__ la,
                                               u16* __restrict__ Mbuf, u16* __restrict__ hseq) {
  __shared__ u16 Ql[64][72], Kl[64][72], KTl[64][72], VTl[64][72], Pl[64][72];
  __shared__ float laS[64], iS[64];
  const int tid = threadIdx.x;
  const int bh = blockIdx.x >> 5, c = blockIdx.x & 31;
  const int lane = tid & 63, w = tid >> 6;
  const int q = lane >> 4, m16 = lane & 15;
  const size_t base = ((size_t)bh * 2048 + c * 64) * 64;
  const int toff = c * 64;   // time offset within the (bh) chain

  // wave 0: chunk-local cumulative log-f scan (fused la_k)
  if (tid < 64) {
    float lg = __logf(gates[(size_t)(64 + bh) * 2048 + toff + tid]);  // f-gate
    #pragma unroll
    for (int off = 1; off < 64; off <<= 1) {
      const float y = __shfl_up(lg, off);
      if (tid >= off) lg += y;
    }
    laS[tid] = lg;
    iS[tid] = gates[(size_t)bh * 2048 + toff + tid];  // i-gate
    la[(size_t)bh * 2048 + toff + tid] = lg;          // for passB/passC
  }
  __syncthreads();

  {
    const int s = tid >> 2, db = (tid & 3) * 16;
    const float wk = __expf(laS[63] - laS[s]) * iS[s];
    const uint4 q0 = *(const uint4*)&Qb[base + s * 64 + db];
    const uint4 q1 = *(const uint4*)&Qb[base + s * 64 + db + 8];
    *(uint4*)&Ql[s][db] = q0;
    *(uint4*)&Ql[s][db + 8] = q1;
    const uint4 k0 = *(const uint4*)&Kb[base + s * 64 + db];
    const uint4 k1 = *(const uint4*)&Kb[base + s * 64 + db + 8];
    *(uint4*)&Kl[s][db] = k0;
    *(uint4*)&Kl[s][db + 8] = k1;
    u16 ktmp[16];
    *(uint4*)&ktmp[0] = k0;
    *(uint4*)&ktmp[8] = k1;
    #pragma unroll
    for (int j = 0; j < 16; j++) KTl[db + j][s] = f2bf(wk * bf2f(ktmp[j]));
    const uint4 v0 = *(const uint4*)&Vb[base + s * 64 + db];
    const uint4 v1 = *(const uint4*)&Vb[base + s * 64 + db + 8];
    u16 vtmp[16];
    *(uint4*)&vtmp[0] = v0;
    *(uint4*)&vtmp[8] = v1;
    #pragma unroll
    for (int j = 0; j < 16; j++) VTl[db + j][s] = vtmp[j];
  }
  __syncthreads();

  // P = (Q K^T) * decay-mask
  f32x4 pacc[4] = {};
  #pragma unroll
  for (int ks = 0; ks < 2; ks++) {
    const bf16x8 aq = *(const bf16x8*)&Ql[w * 16 + m16][ks * 32 + q * 8];
    #pragma unroll
    for (int ni = 0; ni < 4; ni++) {
      const bf16x8 bk = *(const bf16x8*)&Kl[ni * 16 + m16][ks * 32 + q * 8];
      pacc[ni] = __builtin_amdgcn_mfma_f32_16x16x32_bf16(aq, bk, pacc[ni], 0, 0, 0);
    }
  }
  #pragma unroll
  for (int ni = 0; ni < 4; ni++)
    #pragma unroll
    for (int r = 0; r < 4; r++) {
      const int tt = w * 16 + q * 4 + r, ss = ni * 16 + m16;
      float Wts = 0.0f;
      if (ss <= tt) Wts = __expf(laS[tt] - laS[ss]) * iS[ss];
      Pl[tt][ss] = f2bf(pacc[ni][r] * Wts);
    }
  __syncthreads();

  // h_intra = P @ V ; M^T via mfma(bv, ak) -> C[e][d]
  f32x4 hacc[4] = {}, macc[4] = {};
  #pragma unroll
  for (int ks = 0; ks < 2; ks++) {
    const bf16x8 ap = *(const bf16x8*)&Pl[w * 16 + m16][ks * 32 + q * 8];
    const bf16x8 av = *(const bf16x8*)&VTl[w * 16 + m16][ks * 32 + q * 8];
    #pragma unroll
    for (int ni = 0; ni < 4; ni++) {
      const bf16x8 bv = *(const bf16x8*)&VTl[ni * 16 + m16][ks * 32 + q * 8];
      const bf16x8 bk = *(const bf16x8*)&KTl[ni * 16 + m16][ks * 32 + q * 8];
      hacc[ni] = __builtin_amdgcn_mfma_f32_16x16x32_bf16(ap, bv, hacc[ni], 0, 0, 0);
      macc[ni] = __builtin_amdgcn_mfma_f32_16x16x32_bf16(av, bk, macc[ni], 0, 0, 0);
    }
  }

  // vectorized epilogue: stage into Pl (h) and Kl (M), then uint4 stores.
  __syncthreads();   // all Pl (ap operand) reads complete before overwrite
  #pragma unroll
  for (int ni = 0; ni < 4; ni++)
    #pragma unroll
    for (int r = 0; r < 4; r++) {
      const int tt = w * 16 + q * 4 + r, e = ni * 16 + m16;
      Pl[tt][e] = f2bf(hacc[ni][r]);
      Kl[tt][e] = f2bf(macc[ni][r]);
    }
  __syncthreads();
  {
    const int s = tid >> 2, db = (tid & 3) * 16;
    const int b = bh >> 4, h = bh & 15;
    u16* hp = &hseq[((size_t)b * 2048 + c * 64 + s) * 1024 + h * 64 + db];
    *(uint4*)hp       = *(const uint4*)&Pl[s][db];
    *(uint4*)(hp + 8) = *(const uint4*)&Pl[s][db + 8];
    u16* mp = &Mbuf[(((size_t)bh * 32 + c) * 64 + s) * 64 + db];
    *(uint4*)mp       = *(const uint4*)&Kl[s][db];
    *(uint4*)(mp + 8) = *(const uint4*)&Kl[s][db + 8];
  }
}

// ---------------- pass B: inter-chunk state scan (in place, bf16: M^T[c] -> S_prev^T[c]) ----------------
__global__ __launch_bounds__(256) void passB_k(u16* __restrict__ Mbuf,
                                               const float* __restrict__ hidden,
                                               const float* __restrict__ la) {
  const int bh = blockIdx.x >> 4;
  const int e = (blockIdx.x & 15) * 256 + threadIdx.x;   // flat idx in 4096 = [e][d] (transposed)
  __shared__ float Gs[32];
  if (threadIdx.x < 32)
    Gs[threadIdx.x] = __expf(la[(size_t)bh * 2048 + threadIdx.x * 64 + 63]);
  __syncthreads();
  const int eRow = e >> 6, dCol = e & 63;
  float st = hidden[(size_t)bh * 4096 + dCol * 64 + eRow];
  u16* M = &Mbuf[(size_t)bh * 32 * 4096 + e];
  float m_next = bf2f(M[0]);
  #pragma unroll 4
  for (int c = 0; c < 32; c++) {
    const float m_cur = m_next;
    if (c < 31) m_next = bf2f(M[(size_t)(c + 1) * 4096]);
    M[(size_t)c * 4096] = f2bf(st);
    st = Gs[c] * st + m_cur;
  }
}

// ---------------- pass C: h = o * (h_intra + a_t * q^T S_prev) ----------------
__global__ __launch_bounds__(256) void passC_k(const u16* __restrict__ Qb,
                                               const u16* __restrict__ SprevT,
                                               const float* __restrict__ la,
                                               const float* __restrict__ gates,
                                               u16* __restrict__ hseq) {
  __shared__ u16 aQl[64][72], STl[64][72];
  __shared__ float hstage[64][68];   // f32 staging; stride 272 B = 17x16 B (aligned)
  __shared__ float laS[64], oS[64];
  const int tid = threadIdx.x;
  const int bh = blockIdx.x >> 5, c = blockIdx.x & 31;
  const int lane = tid & 63, w = tid >> 6;
  const int q = lane >> 4, m16 = lane & 15;
  const size_t base = ((size_t)bh * 2048 + c * 64) * 64;
  const int toff = c * 64;
  if (tid < 64) {
    laS[tid] = la[(size_t)bh * 2048 + toff + tid];
    oS[tid] = gates[(size_t)(128 + bh) * 2048 + toff + tid];  // o-gate
  }
  {
    const int s = tid >> 2, db = (tid & 3) * 16;
    *(uint4*)&aQl[s][db]     = *(const uint4*)&Qb[base + s * 64 + db];
    *(uint4*)&aQl[s][db + 8] = *(const uint4*)&Qb[base + s * 64 + db + 8];
    const u16* SpT = &SprevT[((size_t)bh * 32 + c) * 4096];
    *(uint4*)&STl[s][db]     = *(const uint4*)&SpT[s * 64 + db];
    *(uint4*)&STl[s][db + 8] = *(const uint4*)&SpT[s * 64 + db + 8];
  }
  __syncthreads();
  f32x4 acc[4] = {};
  #pragma unroll
  for (int ks = 0; ks < 2; ks++) {
    const bf16x8 a = *(const bf16x8*)&aQl[w * 16 + m16][ks * 32 + q * 8];
    #pragma unroll
    for (int ni = 0; ni < 4; ni++) {
      const bf16x8 bb = *(const bf16x8*)&STl[ni * 16 + m16][ks * 32 + q * 8];
      acc[ni] = __builtin_amdgcn_mfma_f32_16x16x32_bf16(a, bb, acc[ni], 0, 0, 0);
    }
  }
  // stage acc (f32), then vectorized RMW of hseq with row-uniform a_t, o
  #pragma unroll
  for (int ni = 0; ni < 4; ni++)
    #pragma unroll
    for (int r = 0; r < 4; r++)
      hstage[w * 16 + q * 4 + r][ni * 16 + m16] = acc[ni][r];
  __syncthreads();
  {
    const int s = tid >> 2, db = (tid & 3) * 16;
    const int b = bh >> 4, h = bh & 15;
    const float a_t = __expf(laS[s]);
    const float o = oS[s];
    u16* hp = &hseq[((size_t)b * 2048 + c * 64 + s) * 1024 + h * 64 + db];
    uint4 h0 = *(const uint4*)hp, h1 = *(const uint4*)(hp + 8);
    u16 hv[16];
    *(uint4*)&hv[0] = h0;
    *(uint4*)&hv[8] = h1;
    float sv[16];
    *(float4*)&sv[0]  = *(const float4*)&hstage[s][db];
    *(float4*)&sv[4]  = *(const float4*)&hstage[s][db + 4];
    *(float4*)&sv[8]  = *(const float4*)&hstage[s][db + 8];
    *(float4*)&sv[12] = *(const float4*)&hstage[s][db + 12];
    u16 ov[16];
    #pragma unroll
    for (int j = 0; j < 16; j++)
      ov[j] = f2bf(o * (bf2f(hv[j]) + a_t * sv[j]));
    *(uint4*)hp       = *(const uint4*)&ov[0];
    *(uint4*)(hp + 8) = *(const uint4*)&ov[8];
  }
}

extern "C" void kernel_launch(void* const* d_in, const int* in_sizes, int n_in,
                              void* d_out, int out_size, void* d_ws, size_t ws_size,
                              hipStream_t stream) {
  (void)in_sizes; (void)n_in; (void)out_size; (void)ws_size;
  const float* x      = (const float*)d_in[0];
  const float* hidden = (const float*)d_in[1];
  const float* w_rms  = (const float*)d_in[2];
  const float* w_qkv  = (const float*)d_in[3];
  const float* w_gate = (const float*)d_in[4];
  const float* w_out  = (const float*)d_in[5];
  float* out = (float*)d_out;

  char* p = (char*)d_ws;
  u16* wqkvT = (u16*)p;  p += (size_t)N1 * 1024 * 2;        // 6.8 MB
  u16* woutT = (u16*)p;  p += (size_t)1024 * 1024 * 2;      // 2.1 MB
  u16* xn    = (u16*)p;  p += (size_t)ROWS * 1024 * 2;      // 16.8 MB
  u16* Qb    = (u16*)p;  p += (size_t)BH * 2048 * 64 * 2;   // 16.8 MB
  u16* Kb    = (u16*)p;  p += (size_t)BH * 2048 * 64 * 2;
  u16* Vb    = (u16*)p;  p += (size_t)BH * 2048 * 64 * 2;
  float* gates = (float*)p; p += (size_t)3 * BH * 2048 * 4; // 1.6 MB
  float* la    = (float*)p; p += (size_t)BH * 2048 * 4;     // 0.5 MB
  u16* Mbuf  = (u16*)p;  p += (size_t)BH * NC * 4096 * 2;   // 16.8 MB (bf16, transposed)
  u16* hseq  = (u16*)p;  p += (size_t)ROWS * 1024 * 2;      // 16.8 MB

  prep_all<<<12320, 256, 0, stream>>>(x, w_rms, xn, w_qkv, w_out, w_gate, wqkvT, woutT);
  gemm_qkv<<<416, 512, 0, stream>>>(xn, wqkvT, Qb, Kb, Vb, gates);
  passA_k<<<BH * NC, 256, 0, stream>>>(Qb, Kb, Vb, gates, la, Mbuf, hseq);
  passB_k<<<BH * 16, 256, 0, stream>>>(Mbuf, hidden, la);
  passC_k<<<BH * NC, 256, 0, stream>>>(Qb, Mbuf, la, gates, hseq);
  gemm_out<<<256, 512, 0, stream>>>(hseq, woutT, x, out);
}